// Round 3
// baseline (81.107 us; speedup 1.0000x reference)
//
#include <hip/hip_runtime.h>
#include <hip/hip_bf16.h>

// pAUC loss:
//   bce(i,j) = -log(clip(sigmoid(pos_i - neg_j), 1e-6, 1-1e-6))
//   out = sum_i topk_j(bce, K=512) / (N_pos * N_neg)
//
// bce is monotone non-decreasing in neg_j for every row, so each row's top-K
// columns are the K largest negatives — ONE global multiset selection.
// Radix select with 10-bit digits (1024 bins): the 8-bit version had a single
// LDS bin covering [0.5,2.0) = 38% of N(0,1) keys -> ~6300 serialized
// same-address LDS atomics on one CU. 1024 bins cap the hottest bin at ~4.4%.

#define TOPK   512
#define SEL_T  1024
#define EPT    16                 // SEL_T * EPT = 16384 >= n_neg
#define ROWS_PER_BLOCK 16
#define KB_T   256
// clip(sigmoid,1e-6,1-1e-6) then -log  ==  clamp(bce, -log(1-eps), -log(eps))
#define BCE_LO 1.0000005e-6f
#define BCE_HI 13.8155106f

// ---------- Kernel A: exact top-k multiset via 4-pass radix select
// (digit widths 10/10/10/2). Keys register-resident (16/thread, 1 block).
// Also zeroes the arrive-counter used by kernel B's last-block finalize.
__global__ __launch_bounds__(SEL_T) void topk_select_kernel(
    const float* __restrict__ neg, int n_neg,
    float* __restrict__ topk, int k,
    unsigned int* __restrict__ counter) {
    __shared__ unsigned int bins[1024];
    __shared__ unsigned int suf[1024];
    __shared__ unsigned int wtot[16], wsuf[16];
    __shared__ unsigned int bc_digit, bc_kk;
    __shared__ unsigned int out_gt, out_eq;

    const int tid  = threadIdx.x;
    const int lane = tid & 63;
    const int wv   = tid >> 6;

    if (tid == 0) *counter = 0u;   // for kernel B's last-block pattern

    unsigned int keys[EPT];
    #pragma unroll
    for (int t = 0; t < EPT; ++t) {
        int i = t * SEL_T + tid;
        unsigned int key = 0u;              // pad = smallest key, never selected
        if (i < n_neg) {
            unsigned int u = __float_as_uint(neg[i]);
            key = u ^ ((u >> 31) ? 0xFFFFFFFFu : 0x80000000u);
        }
        keys[t] = key;
    }

    const int      shifts[4] = {22, 12, 2, 0};
    const unsigned nbv[4]    = {1024u, 1024u, 1024u, 4u};

    unsigned int prefix = 0u, pmask = 0u, kk = (unsigned)k;
    for (int pass = 0; pass < 4; ++pass) {
        const int shift       = shifts[pass];
        const unsigned nb     = nbv[pass];
        const unsigned dmask  = nb - 1u;
        if (tid < (int)nb) bins[tid] = 0u;
        __syncthreads();
        #pragma unroll
        for (int t = 0; t < EPT; ++t) {
            unsigned int ky = keys[t];
            if ((ky & pmask) == prefix)
                atomicAdd(&bins[(ky >> shift) & dmask], 1u);
        }
        __syncthreads();
        // suffix sums: suf[d] = # participating keys with digit >= d
        unsigned int c = (tid < (int)nb) ? bins[tid] : 0u;
        unsigned int part = c;
        #pragma unroll
        for (int off = 1; off < 64; off <<= 1) {
            unsigned int v = __shfl_down(part, off, 64);
            if (lane + off < 64) part += v;
        }
        if (lane == 0) wtot[wv] = part;     // wave total (bins wv*64 .. wv*64+63)
        __syncthreads();
        if (tid == 0) {
            unsigned int run = 0u;
            for (int w = 15; w >= 0; --w) { wsuf[w] = run; run += wtot[w]; }
        }
        __syncthreads();
        if (tid < (int)nb) suf[tid] = part + wsuf[wv];
        __syncthreads();
        // exactly one digit satisfies: suf[d] >= kk > suf[d+1]
        if (tid < (int)nb) {
            unsigned int s_here = suf[tid];
            unsigned int s_next = (tid == (int)nb - 1) ? 0u : suf[tid + 1];
            if (s_here >= kk && s_next < kk) {
                bc_digit = (unsigned)tid;
                bc_kk = kk - s_next;
            }
        }
        __syncthreads();
        prefix |= bc_digit << shift;
        kk = bc_kk;
        pmask |= dmask << shift;
        __syncthreads();   // protect bc_/bins reuse across passes
    }

    const unsigned int T = prefix;          // exact threshold key
    if (tid == 0) { out_gt = 0u; out_eq = 0u; }
    __syncthreads();
    const unsigned int n_gt = (unsigned)k - kk;   // # strictly-greater selected
    #pragma unroll
    for (int t = 0; t < EPT; ++t) {
        unsigned int ky = keys[t];
        if (ky > T) {
            unsigned int idx = atomicAdd(&out_gt, 1u);
            unsigned int u = (ky >> 31) ? (ky ^ 0x80000000u) : (ky ^ 0xFFFFFFFFu);
            topk[idx] = __uint_as_float(u);
        } else if (ky == T) {
            unsigned int idx = atomicAdd(&out_eq, 1u);
            if (idx < kk) {
                unsigned int u = (ky >> 31) ? (ky ^ 0x80000000u) : (ky ^ 0xFFFFFFFFu);
                topk[n_gt + idx] = __uint_as_float(u);
            }
        }
    }
}

// ---------- Kernel B: partial bce sums + fused last-block finalize.
// Top-k values in registers (2/thread); cross-XCD visibility via agent-scope
// atomics (per-XCD L2s are not coherent for plain loads).
__global__ __launch_bounds__(KB_T) void pauc_sum_finalize_kernel(
    const float* __restrict__ pos, int n_pos,
    const float* __restrict__ topk, int k,
    float* __restrict__ partials, unsigned int* __restrict__ counter,
    float* __restrict__ out, float inv_denom, int nblocks) {
    const int tid = threadIdx.x;
    const bool c0 = tid < k;
    const bool c1 = tid + KB_T < k;
    const float tv0 = c0 ? topk[tid] : 0.0f;
    const float tv1 = c1 ? topk[tid + KB_T] : 0.0f;
    const int row0 = blockIdx.x * ROWS_PER_BLOCK;
    float acc = 0.0f;
    #pragma unroll
    for (int r = 0; r < ROWS_PER_BLOCK; ++r) {
        int row = row0 + r;
        if (row >= n_pos) break;
        float pv = pos[row];
        // -log(clip(sigmoid(pv - tv))) = clamp(log(1 + exp(tv - pv)))
        float b0 = __logf(1.0f + __expf(tv0 - pv));
        float b1 = __logf(1.0f + __expf(tv1 - pv));
        b0 = fminf(fmaxf(b0, BCE_LO), BCE_HI);
        b1 = fminf(fmaxf(b1, BCE_LO), BCE_HI);
        acc += (c0 ? b0 : 0.0f) + (c1 ? b1 : 0.0f);
    }
    #pragma unroll
    for (int off = 32; off > 0; off >>= 1) acc += __shfl_down(acc, off, 64);
    __shared__ float s_red[KB_T / 64];
    const int lane = tid & 63, wv = tid >> 6;
    if (lane == 0) s_red[wv] = acc;
    __syncthreads();
    __shared__ bool s_last;
    if (tid == 0) {
        float t = s_red[0] + s_red[1] + s_red[2] + s_red[3];
        __hip_atomic_store(&partials[blockIdx.x], t,
                           __ATOMIC_RELAXED, __HIP_MEMORY_SCOPE_AGENT);
        unsigned int prev = __hip_atomic_fetch_add(counter, 1u,
                           __ATOMIC_ACQ_REL, __HIP_MEMORY_SCOPE_AGENT);
        s_last = (prev == (unsigned)(nblocks - 1));
    }
    __syncthreads();
    if (s_last) {
        float a = 0.0f;
        for (int i = tid; i < nblocks; i += KB_T)
            a += __hip_atomic_load(&partials[i],
                                   __ATOMIC_RELAXED, __HIP_MEMORY_SCOPE_AGENT);
        #pragma unroll
        for (int off = 32; off > 0; off >>= 1) a += __shfl_down(a, off, 64);
        if (lane == 0) s_red[wv] = a;
        __syncthreads();
        if (tid == 0)
            out[0] = (s_red[0] + s_red[1] + s_red[2] + s_red[3]) * inv_denom;
    }
}

extern "C" void kernel_launch(void* const* d_in, const int* in_sizes, int n_in,
                              void* d_out, int out_size, void* d_ws, size_t ws_size,
                              hipStream_t stream) {
    const float* neg = (const float*)d_in[0];   // score_neg, 16384
    const float* pos = (const float*)d_in[1];   // score_pos, 8192
    const int n_neg = in_sizes[0];
    const int n_pos = in_sizes[1];
    float* out = (float*)d_out;
    float* ws  = (float*)d_ws;

    int k = TOPK; if (k > n_neg) k = n_neg;
    float* topk_buf = ws;                                  // [0, 512)
    unsigned int* counter = (unsigned int*)(ws + TOPK);    // [512]
    float* partials = ws + TOPK + 1;                       // [513, 513+nb)

    const int nb = (n_pos + ROWS_PER_BLOCK - 1) / ROWS_PER_BLOCK;   // 512

    topk_select_kernel<<<1, SEL_T, 0, stream>>>(neg, n_neg, topk_buf, k, counter);
    const float inv_denom = (float)(1.0 / ((double)n_pos * (double)n_neg));
    pauc_sum_finalize_kernel<<<nb, KB_T, 0, stream>>>(
        pos, n_pos, topk_buf, k, partials, counter, out, inv_denom, nb);
}